// Round 10
// baseline (120.943 us; speedup 1.0000x reference)
//
#include <hip/hip_runtime.h>
#include <math.h>

#define KOBJ 512
#define KTW 8       // packed row (32 B): xh[4] (8 fp16), s2, w_rep, w_att, pad
#define TK 128      // k-tile per pairs block
#define NTILE (KOBJ / TK)   // 4
#define HB 4        // hits per thread (register blocking)
#define HCH (256 * HB)      // 1024 hits per block
#define MPREP 128   // prep blocks
#define GGATH 16    // gather blocks (32 objects each)

typedef _Float16 half2_t __attribute__((ext_vector_type(2)));

__device__ __forceinline__ float wave_red_f(float v) {
  #pragma unroll
  for (int off = 32; off > 0; off >>= 1) v += __shfl_down(v, off, 64);
  return v;
}

// fast atanh(b)^2 + 1 ; b in (0, 0.96]
__device__ __forceinline__ float q_of_beta(float b) {
  float a = 0.5f * __logf((1.f + b) / (1.f - b));
  return fmaf(a, a, 1.f);
}

// acc + y.h0*k.h0 + ... over 8 fp16 components, fp32 accumulate.
// Fixed op order -> bit-identical between in-loop and own-undo paths.
__device__ __forceinline__ float dot8h(uint4 kx, const uint* y, float acc) {
#if __has_builtin(__builtin_amdgcn_fdot2)
  acc = __builtin_amdgcn_fdot2(__builtin_bit_cast(half2_t, y[0]),
                               __builtin_bit_cast(half2_t, kx.x), acc, false);
  acc = __builtin_amdgcn_fdot2(__builtin_bit_cast(half2_t, y[1]),
                               __builtin_bit_cast(half2_t, kx.y), acc, false);
  acc = __builtin_amdgcn_fdot2(__builtin_bit_cast(half2_t, y[2]),
                               __builtin_bit_cast(half2_t, kx.z), acc, false);
  acc = __builtin_amdgcn_fdot2(__builtin_bit_cast(half2_t, y[3]),
                               __builtin_bit_cast(half2_t, kx.w), acc, false);
#else
  const uint kk[4] = {kx.x, kx.y, kx.z, kx.w};
  #pragma unroll
  for (int c = 0; c < 4; c++) {
    half2_t a = __builtin_bit_cast(half2_t, y[c]);
    half2_t b = __builtin_bit_cast(half2_t, kk[c]);
    acc = fmaf((float)a.x, (float)b.x, acc);
    acc = fmaf((float)a.y, (float)b.y, acc);
  }
#endif
  return acc;
}

// ---------------------------------------------------------------------------
// Pass 1: 128 blocks, ~3.7 hits/thread. LDS-aggregated per-object argmax(q)
// and counts flushed as per-block partial tables; payload losses block-reduced.
// ---------------------------------------------------------------------------
__global__ __launch_bounds__(256) void
k_prep(const float* __restrict__ beta, const int* __restrict__ oid,
       const float* __restrict__ energy, const float* __restrict__ eph,
       const float* __restrict__ mom, const float* __restrict__ mph,
       const float* __restrict__ logits, const int* __restrict__ pid,
       unsigned long long* __restrict__ amax_part,
       unsigned* __restrict__ cnt_part,
       float* __restrict__ scal_part, int n) {
  __shared__ unsigned long long lmax[KOBJ];
  __shared__ unsigned lcnt[KOBJ];
  for (int t = threadIdx.x; t < KOBJ; t += 256) { lmax[t] = 0ull; lcnt[t] = 0u; }
  __syncthreads();

  float e_t = 0.f, p_t = 0.f, pid_t = 0.f, noise_t = 0.f, ncnt = 0.f, mcnt = 0.f;
  for (int i = blockIdx.x * 256 + threadIdx.x; i < n; i += MPREP * 256) {
    float b = beta[i];
    int o = oid[i];
    if (o > 0) {
      float q = q_of_beta(b);
      // pack (q bits | ~i): max-q wins, ties -> smallest index (argmax semantics)
      unsigned long long key = ((unsigned long long)__float_as_uint(q) << 32)
                             | (unsigned long long)(unsigned)(~(unsigned)i);
      atomicMax(&lmax[o - 1], key);
      atomicAdd(&lcnt[o - 1], 1u);
      mcnt += 1.f;
      float de = energy[i] - eph[i];
      e_t = fmaf(de, de, e_t);
      float p0 = mom[3*i+0] - mph[3*i+0];
      float p1 = mom[3*i+1] - mph[3*i+1];
      float p2 = mom[3*i+2] - mph[3*i+2];
      p_t = fmaf(p0, p0, p_t); p_t = fmaf(p1, p1, p_t); p_t = fmaf(p2, p2, p_t);
      const float* lg = logits + 6*i;
      float l0=lg[0], l1=lg[1], l2=lg[2], l3=lg[3], l4=lg[4], l5=lg[5];
      float mx = fmaxf(fmaxf(fmaxf(l0,l1),fmaxf(l2,l3)), fmaxf(l4,l5));
      float s = __expf(l0-mx)+__expf(l1-mx)+__expf(l2-mx)
              + __expf(l3-mx)+__expf(l4-mx)+__expf(l5-mx);
      int pc = pid[i];
      float lp = (pc==0)?l0:(pc==1)?l1:(pc==2)?l2:(pc==3)?l3:(pc==4)?l4:l5;
      pid_t += mx + __logf(s) - lp;
    } else {
      noise_t += b;
      ncnt += 1.f;
    }
  }
  __syncthreads();

  for (int t = threadIdx.x; t < KOBJ; t += 256) {
    amax_part[(size_t)blockIdx.x * KOBJ + t] = lmax[t];
    cnt_part[(size_t)blockIdx.x * KOBJ + t]  = lcnt[t];
  }

  float vals[6] = {e_t, p_t, pid_t, noise_t, ncnt, mcnt};
  #pragma unroll
  for (int j = 0; j < 6; j++) vals[j] = wave_red_f(vals[j]);
  __shared__ float sred[4][6];
  int w = threadIdx.x >> 6, l = threadIdx.x & 63;
  if (l == 0) {
    #pragma unroll
    for (int j = 0; j < 6; j++) sred[w][j] = vals[j];
  }
  __syncthreads();
  if (threadIdx.x == 0) {
    #pragma unroll
    for (int j = 0; j < 6; j++)
      scal_part[blockIdx.x * 8 + j] = sred[0][j]+sred[1][j]+sred[2][j]+sred[3][j];
  }
}

// ---------------------------------------------------------------------------
// Pass 2: 16 blocks x 256 threads. Block b owns objects [b*32,(b+1)*32);
// thread = (m_chunk 0..7, object 0..31). Reduce 128 partials, decode the
// condensation point, emit packed fp16 row + per-block coward partial.
// ---------------------------------------------------------------------------
__global__ __launch_bounds__(256) void
k_gather(const float* __restrict__ x, const float* __restrict__ beta,
         const unsigned long long* __restrict__ amax_part,
         const unsigned* __restrict__ cnt_part,
         uint* __restrict__ ktab, float* __restrict__ cow_part, int n) {
  int ko = threadIdx.x & 31;          // object within block
  int chunk = threadIdx.x >> 5;       // 0..7 m-chunk
  int k = blockIdx.x * 32 + ko;       // global object id - 1
  const int mpc = MPREP / 8;          // 16
  int m0 = chunk * mpc, m1 = m0 + mpc;

  unsigned long long key = 0ull;
  unsigned cnt = 0u;
  for (int m = m0; m < m1; m++) {
    unsigned long long km = amax_part[(size_t)m * KOBJ + k];
    key = (km > key) ? km : key;
    cnt += cnt_part[(size_t)m * KOBJ + k];
  }
  __shared__ unsigned long long skey[8][32];
  __shared__ unsigned scnt[8][32];
  skey[chunk][ko] = key;
  scnt[chunk][ko] = cnt;
  __syncthreads();

  float cow = 0.f;
  if (chunk == 0) {
    #pragma unroll
    for (int c = 1; c < 8; c++) {
      unsigned long long kc = skey[c][ko];
      key = (kc > key) ? kc : key;
      cnt += scnt[c][ko];
    }
    unsigned idx = ~(unsigned)(key & 0xffffffffull);
    float q_k = __uint_as_float((unsigned)(key >> 32));
    const float4* xp = (const float4*)x;
    float4 xa = xp[2 * (size_t)idx];
    float4 xb = xp[2 * (size_t)idx + 1];
    float xv[8] = {xa.x, xa.y, xa.z, xa.w, xb.x, xb.y, xb.z, xb.w};
    float s2 = 0.f;
    #pragma unroll
    for (int c = 0; c < 8; c++) s2 = fmaf(xv[c], xv[c], s2);
    uint* kt = ktab + (size_t)k * KTW;
    #pragma unroll
    for (int c = 0; c < 4; c++) {
      half2_t hp = { (_Float16)xv[2*c], (_Float16)xv[2*c+1] };
      kt[c] = __builtin_bit_cast(uint, hp);
    }
    kt[4] = __float_as_uint(s2);
    kt[5] = __float_as_uint(q_k / ((float)(n - (int)cnt) + 1e-9f));  // w_rep
    kt[6] = __float_as_uint(q_k / ((float)cnt + 1e-9f));             // w_att
    kt[7] = 0u;
    cow = 1.f - beta[idx];
  }
  cow = wave_red_f(cow);   // non-chunk-0 lanes contribute 0
  if (threadIdx.x == 0) cow_part[blockIdx.x] = cow;
}

// ---------------------------------------------------------------------------
// Pass 3 (hot): 2D grid (118 hit-blocks x 4 k-tiles). HB=4 hits/thread in
// registers (fp16 packed y = -2x); per k: one b128 LDS broadcast row read,
// then per hit 4 v_dot2_f32_f16 + 1 cmp (hinge folded into thr[h] = 1-|xi|^2).
// sqrt only on accepted pairs. Own-object term undone bit-exactly after loop.
// ---------------------------------------------------------------------------
__global__ __launch_bounds__(256, 4) void
k_pairs(const float* __restrict__ x, const float* __restrict__ beta,
        const int* __restrict__ oid, const uint* __restrict__ ktab,
        float* __restrict__ pairs_part, int n) {
  __shared__ __align__(16) uint skt[TK * KTW];   // 4 KiB
  const int tid = threadIdx.x;
  const int tile0 = blockIdx.y * TK;
  const int hbase = blockIdx.x * HCH;

  for (int t = tid; t < TK * KTW; t += 256)
    skt[t] = ktab[(size_t)tile0 * KTW + t];
  __syncthreads();

  // load HB hits into registers
  uint yh[HB][4];
  float thr[HB], bh[HB], qi[HB];
  int own[HB];
  const float4* xp = (const float4*)x;
  #pragma unroll
  for (int h = 0; h < HB; h++) {
    int i = hbase + h * 256 + tid;
    if (i < n) {
      float4 xa = xp[2 * (size_t)i];
      float4 xb = xp[2 * (size_t)i + 1];
      float xi[8] = {xa.x, xa.y, xa.z, xa.w, xb.x, xb.y, xb.z, xb.w};
      float s = 0.f;
      #pragma unroll
      for (int c = 0; c < 8; c++) s = fmaf(xi[c], xi[c], s);
      bh[h] = s;
      thr[h] = 1.f - s;     // accept iff d2' < thr  (d2 = d2' + |xi|^2 < 1)
      #pragma unroll
      for (int c = 0; c < 4; c++) {
        half2_t hy = { (_Float16)(-2.f * xi[2*c]), (_Float16)(-2.f * xi[2*c+1]) };
        yh[h][c] = __builtin_bit_cast(uint, hy);
      }
      qi[h] = q_of_beta(beta[i]);
      own[h] = oid[i] - 1 - tile0;   // own object within tile (or out of range)
    } else {
      #pragma unroll
      for (int c = 0; c < 4; c++) yh[h][c] = 0u;
      bh[h] = 0.f;
      thr[h] = -1e30f;               // never accept
      qi[h] = 0.f;
      own[h] = -1;
    }
  }

  float att = 0.f, rep = 0.f, nrep = 0.f;
  #pragma unroll 2
  for (int k = 0; k < TK; k++) {
    const uint* kr = &skt[k * KTW];
    uint4 kx = *(const uint4*)kr;            // ds_read_b128, wave-uniform
    float s2 = __uint_as_float(kr[4]);
    float wr = __uint_as_float(kr[5]);
    #pragma unroll
    for (int h = 0; h < HB; h++) {
      float dp = dot8h(kx, yh[h], s2);       // s2 - 2*xi.xk (fp16 in, fp32 acc)
      if (dp < thr[h]) {                     // d2 < 1
        float d2 = dp + bh[h];
        float dist = sqrtf(fmaxf(d2, 1e-12f));
        rep = fmaf(qi[h] * (1.f - dist), wr, rep);
        nrep += 1.f;
      }
    }
  }

  // own-object: attractive term + bit-exact undo of in-loop repulsive term
  #pragma unroll
  for (int h = 0; h < HB; h++) {
    int ko = own[h];
    if (ko >= 0 && ko < TK) {
      const uint* kr = &skt[ko * KTW];
      uint4 kx = *(const uint4*)kr;
      float s2 = __uint_as_float(kr[4]);
      float wr = __uint_as_float(kr[5]);
      float wa = __uint_as_float(kr[6]);
      float dp = dot8h(kx, yh[h], s2);       // identical op order -> same bits
      float d2 = dp + bh[h];
      att = fmaf(qi[h] * fmaxf(d2, 0.f), wa, att);
      if (dp < thr[h]) {
        float dist = sqrtf(fmaxf(d2, 1e-12f));
        rep = fmaf(-qi[h] * (1.f - dist), wr, rep);
        nrep -= 1.f;
      }
    }
  }

  att = wave_red_f(att);
  rep = wave_red_f(rep);
  nrep = wave_red_f(nrep);
  __shared__ float sred[4][3];
  int w = tid >> 6, l = tid & 63;
  if (l == 0) { sred[w][0] = att; sred[w][1] = rep; sred[w][2] = nrep; }
  __syncthreads();
  if (tid == 0) {
    int bid = blockIdx.y * gridDim.x + blockIdx.x;
    pairs_part[bid * 4 + 0] = sred[0][0]+sred[1][0]+sred[2][0]+sred[3][0];
    pairs_part[bid * 4 + 1] = sred[0][1]+sred[1][1]+sred[2][1]+sred[3][1];
    pairs_part[bid * 4 + 2] = sred[0][2]+sred[1][2]+sred[2][2]+sred[3][2];
  }
}

// ---------------------------------------------------------------------------
// Pass 4: combine everything.
// ---------------------------------------------------------------------------
__global__ __launch_bounds__(256) void
k_finalize(const float* __restrict__ pairs_part, int nblk_tot,
           const float* __restrict__ scal_part,
           const float* __restrict__ cow_part, float* __restrict__ out) {
  float v[9] = {0,0,0,0,0,0,0,0,0};  // att, rep, nrep, e, p, pid, noise, ncnt, mcnt
  for (int b = threadIdx.x; b < nblk_tot; b += 256) {
    v[0] += pairs_part[b * 4 + 0];
    v[1] += pairs_part[b * 4 + 1];
    v[2] += pairs_part[b * 4 + 2];
  }
  for (int m = threadIdx.x; m < MPREP; m += 256) {
    #pragma unroll
    for (int j = 0; j < 6; j++) v[3 + j] += scal_part[m * 8 + j];
  }
  #pragma unroll
  for (int j = 0; j < 9; j++) v[j] = wave_red_f(v[j]);
  __shared__ float sred[4][9];
  int w = threadIdx.x >> 6, l = threadIdx.x & 63;
  if (l == 0) {
    #pragma unroll
    for (int j = 0; j < 9; j++) sred[w][j] = v[j];
  }
  __syncthreads();
  if (threadIdx.x == 0) {
    float t[9];
    #pragma unroll
    for (int j = 0; j < 9; j++) t[j] = sred[0][j]+sred[1][j]+sred[2][j]+sred[3][j];
    float cow = 0.f;
    #pragma unroll
    for (int g = 0; g < GGATH; g++) cow += cow_part[g];
    float v_att  = t[0] / (float)KOBJ;
    float v_rep  = t[1] / (float)KOBJ;
    float n_rep  = t[2];
    float l_cow  = cow / (float)KOBJ;
    float l_noise = t[6] / t[7];
    float oc = v_att + v_rep + l_cow + l_noise;
    float nm = t[8];
    float e_loss  = t[3] / nm;
    float p_loss  = t[4] / (nm * 3.f);
    float pid_loss = t[5] / nm;
    out[0] = v_att;
    out[1] = v_rep;
    out[2] = l_cow;
    out[3] = l_noise;
    out[4] = n_rep;
    out[5] = oc;
    out[6] = e_loss;
    out[7] = p_loss;
    out[8] = pid_loss;
    out[9] = oc + e_loss + p_loss + pid_loss;
  }
}

extern "C" void kernel_launch(void* const* d_in, const int* in_sizes, int n_in,
                              void* d_out, int out_size, void* d_ws, size_t ws_size,
                              hipStream_t stream) {
  const float* beta   = (const float*)d_in[0];
  const float* x      = (const float*)d_in[1];
  const int*   oid    = (const int*)d_in[2];
  const float* energy = (const float*)d_in[3];
  const float* eph    = (const float*)d_in[4];
  const float* mom    = (const float*)d_in[5];
  const float* mph    = (const float*)d_in[6];
  const float* logits = (const float*)d_in[7];
  const int*   pid    = (const int*)d_in[8];
  float* out = (float*)d_out;
  const int n = in_sizes[0];
  const int nhb = (n + HCH - 1) / HCH;      // hit-chunks (118)
  const int nblk_tot = nhb * NTILE;         // 472

  char* base = (char*)d_ws;
  size_t off = 0;
  uint*  ktab       = (uint*)(base + off);  off += (size_t)KOBJ * KTW * 4;
  float* cow_part   = (float*)(base + off); off += GGATH * 4;
  float* pairs_part = (float*)(base + off); off += (size_t)nblk_tot * 4 * 4;
  off = (off + 255) & ~(size_t)255;
  unsigned long long* amax_part = (unsigned long long*)(base + off); off += (size_t)MPREP * KOBJ * 8;
  unsigned* cnt_part = (unsigned*)(base + off);                      off += (size_t)MPREP * KOBJ * 4;
  float* scal_part   = (float*)(base + off);                         off += (size_t)MPREP * 8 * 4;

  k_prep<<<MPREP, 256, 0, stream>>>(beta, oid, energy, eph, mom, mph, logits, pid,
                                    amax_part, cnt_part, scal_part, n);
  k_gather<<<GGATH, 256, 0, stream>>>(x, beta, amax_part, cnt_part, ktab, cow_part, n);
  k_pairs<<<dim3(nhb, NTILE), 256, 0, stream>>>(x, beta, oid, ktab, pairs_part, n);
  k_finalize<<<1, 256, 0, stream>>>(pairs_part, nblk_tot, scal_part, cow_part, out);
}

// Round 11
// 114.713 us; speedup vs baseline: 1.0543x; 1.0543x over previous
//
#include <hip/hip_runtime.h>
#include <math.h>

#define KOBJ 512
#define KTW 8       // packed row (32 B): xh[4] (8 fp16), s2, w_rep, w_att, pad
#define TK 32       // k-tile per pairs block
#define NTILE (KOBJ / TK)   // 16
#define HB 8        // hits per thread (register blocking)
#define HCH (256 * HB)      // 2048 hits per block
#define MPREP 512   // prep blocks (<=1 hit/thread at N=120000)
#define GGATH 16    // gather blocks (32 objects each)

typedef _Float16 half2_t __attribute__((ext_vector_type(2)));

__device__ __forceinline__ float wave_red_f(float v) {
  #pragma unroll
  for (int off = 32; off > 0; off >>= 1) v += __shfl_down(v, off, 64);
  return v;
}

// fast atanh(b)^2 + 1 ; b in (0, 0.96]
__device__ __forceinline__ float q_of_beta(float b) {
  float a = 0.5f * __logf((1.f + b) / (1.f - b));
  return fmaf(a, a, 1.f);
}

// acc + y.h0*k.h0 + ... over 8 fp16 components, fp32 accumulate.
// Fixed op order -> bit-identical between in-loop and own-undo paths.
__device__ __forceinline__ float dot8h(uint4 kx, const uint* y, float acc) {
#if __has_builtin(__builtin_amdgcn_fdot2)
  acc = __builtin_amdgcn_fdot2(__builtin_bit_cast(half2_t, y[0]),
                               __builtin_bit_cast(half2_t, kx.x), acc, false);
  acc = __builtin_amdgcn_fdot2(__builtin_bit_cast(half2_t, y[1]),
                               __builtin_bit_cast(half2_t, kx.y), acc, false);
  acc = __builtin_amdgcn_fdot2(__builtin_bit_cast(half2_t, y[2]),
                               __builtin_bit_cast(half2_t, kx.z), acc, false);
  acc = __builtin_amdgcn_fdot2(__builtin_bit_cast(half2_t, y[3]),
                               __builtin_bit_cast(half2_t, kx.w), acc, false);
#else
  const uint kk[4] = {kx.x, kx.y, kx.z, kx.w};
  #pragma unroll
  for (int c = 0; c < 4; c++) {
    half2_t a = __builtin_bit_cast(half2_t, y[c]);
    half2_t b = __builtin_bit_cast(half2_t, kk[c]);
    acc = fmaf((float)a.x, (float)b.x, acc);
    acc = fmaf((float)a.y, (float)b.y, acc);
  }
#endif
  return acc;
}

// ---------------------------------------------------------------------------
// Pass 1: 512 blocks, <=1 hit/thread. LDS-aggregated per-object argmax(q) /
// counts flushed as per-block partial tables; payload losses block-reduced.
// ---------------------------------------------------------------------------
__global__ __launch_bounds__(256) void
k_prep(const float* __restrict__ beta, const int* __restrict__ oid,
       const float* __restrict__ energy, const float* __restrict__ eph,
       const float* __restrict__ mom, const float* __restrict__ mph,
       const float* __restrict__ logits, const int* __restrict__ pid,
       unsigned long long* __restrict__ amax_part,
       unsigned* __restrict__ cnt_part,
       float* __restrict__ scal_part, int n) {
  __shared__ unsigned long long lmax[KOBJ];
  __shared__ unsigned lcnt[KOBJ];
  for (int t = threadIdx.x; t < KOBJ; t += 256) { lmax[t] = 0ull; lcnt[t] = 0u; }
  __syncthreads();

  float e_t = 0.f, p_t = 0.f, pid_t = 0.f, noise_t = 0.f, ncnt = 0.f, mcnt = 0.f;
  for (int i = blockIdx.x * 256 + threadIdx.x; i < n; i += MPREP * 256) {
    float b = beta[i];
    int o = oid[i];
    if (o > 0) {
      float q = q_of_beta(b);
      // pack (q bits | ~i): max-q wins, ties -> smallest index (argmax semantics)
      unsigned long long key = ((unsigned long long)__float_as_uint(q) << 32)
                             | (unsigned long long)(unsigned)(~(unsigned)i);
      atomicMax(&lmax[o - 1], key);
      atomicAdd(&lcnt[o - 1], 1u);
      mcnt += 1.f;
      float de = energy[i] - eph[i];
      e_t = fmaf(de, de, e_t);
      float p0 = mom[3*i+0] - mph[3*i+0];
      float p1 = mom[3*i+1] - mph[3*i+1];
      float p2 = mom[3*i+2] - mph[3*i+2];
      p_t = fmaf(p0, p0, p_t); p_t = fmaf(p1, p1, p_t); p_t = fmaf(p2, p2, p_t);
      const float* lg = logits + 6*i;
      float l0=lg[0], l1=lg[1], l2=lg[2], l3=lg[3], l4=lg[4], l5=lg[5];
      float mx = fmaxf(fmaxf(fmaxf(l0,l1),fmaxf(l2,l3)), fmaxf(l4,l5));
      float s = __expf(l0-mx)+__expf(l1-mx)+__expf(l2-mx)
              + __expf(l3-mx)+__expf(l4-mx)+__expf(l5-mx);
      int pc = pid[i];
      float lp = (pc==0)?l0:(pc==1)?l1:(pc==2)?l2:(pc==3)?l3:(pc==4)?l4:l5;
      pid_t += mx + __logf(s) - lp;
    } else {
      noise_t += b;
      ncnt += 1.f;
    }
  }
  __syncthreads();

  for (int t = threadIdx.x; t < KOBJ; t += 256) {
    amax_part[(size_t)blockIdx.x * KOBJ + t] = lmax[t];
    cnt_part[(size_t)blockIdx.x * KOBJ + t]  = lcnt[t];
  }

  float vals[6] = {e_t, p_t, pid_t, noise_t, ncnt, mcnt};
  #pragma unroll
  for (int j = 0; j < 6; j++) vals[j] = wave_red_f(vals[j]);
  __shared__ float sred[4][6];
  int w = threadIdx.x >> 6, l = threadIdx.x & 63;
  if (l == 0) {
    #pragma unroll
    for (int j = 0; j < 6; j++) sred[w][j] = vals[j];
  }
  __syncthreads();
  if (threadIdx.x == 0) {
    #pragma unroll
    for (int j = 0; j < 6; j++)
      scal_part[blockIdx.x * 8 + j] = sred[0][j]+sred[1][j]+sred[2][j]+sred[3][j];
  }
}

// ---------------------------------------------------------------------------
// Pass 2: 16 blocks x 256 threads. Block b owns objects [b*32,(b+1)*32);
// thread = (m_chunk 0..7, object 0..31). Reduce 512 partials, decode the
// condensation point, emit packed fp16 row + per-block coward partial.
// ---------------------------------------------------------------------------
__global__ __launch_bounds__(256) void
k_gather(const float* __restrict__ x, const float* __restrict__ beta,
         const unsigned long long* __restrict__ amax_part,
         const unsigned* __restrict__ cnt_part,
         uint* __restrict__ ktab, float* __restrict__ cow_part, int n) {
  int ko = threadIdx.x & 31;          // object within block
  int chunk = threadIdx.x >> 5;       // 0..7 m-chunk
  int k = blockIdx.x * 32 + ko;       // global object id - 1
  const int mpc = MPREP / 8;          // 64
  int m0 = chunk * mpc, m1 = m0 + mpc;

  unsigned long long key = 0ull;
  unsigned cnt = 0u;
  for (int m = m0; m < m1; m++) {
    unsigned long long km = amax_part[(size_t)m * KOBJ + k];
    key = (km > key) ? km : key;
    cnt += cnt_part[(size_t)m * KOBJ + k];
  }
  __shared__ unsigned long long skey[8][32];
  __shared__ unsigned scnt[8][32];
  skey[chunk][ko] = key;
  scnt[chunk][ko] = cnt;
  __syncthreads();

  float cow = 0.f;
  if (chunk == 0) {
    #pragma unroll
    for (int c = 1; c < 8; c++) {
      unsigned long long kc = skey[c][ko];
      key = (kc > key) ? kc : key;
      cnt += scnt[c][ko];
    }
    unsigned idx = ~(unsigned)(key & 0xffffffffull);
    float q_k = __uint_as_float((unsigned)(key >> 32));
    const float4* xp = (const float4*)x;
    float4 xa = xp[2 * (size_t)idx];
    float4 xb = xp[2 * (size_t)idx + 1];
    float xv[8] = {xa.x, xa.y, xa.z, xa.w, xb.x, xb.y, xb.z, xb.w};
    float s2 = 0.f;
    #pragma unroll
    for (int c = 0; c < 8; c++) s2 = fmaf(xv[c], xv[c], s2);
    uint* kt = ktab + (size_t)k * KTW;
    #pragma unroll
    for (int c = 0; c < 4; c++) {
      half2_t hp = { (_Float16)xv[2*c], (_Float16)xv[2*c+1] };
      kt[c] = __builtin_bit_cast(uint, hp);
    }
    kt[4] = __float_as_uint(s2);
    kt[5] = __float_as_uint(q_k / ((float)(n - (int)cnt) + 1e-9f));  // w_rep
    kt[6] = __float_as_uint(q_k / ((float)cnt + 1e-9f));             // w_att
    kt[7] = 0u;
    cow = 1.f - beta[idx];
  }
  cow = wave_red_f(cow);   // non-chunk-0 lanes contribute 0
  if (threadIdx.x == 0) cow_part[blockIdx.x] = cow;
}

// ---------------------------------------------------------------------------
// Pass 3 (hot): 2D grid (59 hit-blocks x 16 k-tiles = 944 blocks). HB=8
// hits/thread in registers (fp16 packed y = -2x); per k: one b128+b64 LDS
// broadcast row read serves 64 lanes x 8 hits = 512 pairs; per pair 4
// v_dot2_f32_f16 + 1 cmp (hinge folded into thr[h] = 1-|xi|^2). sqrt only on
// accepted pairs. Own-object term undone bit-exactly after the loop.
// ---------------------------------------------------------------------------
__global__ __launch_bounds__(256, 4) void
k_pairs(const float* __restrict__ x, const float* __restrict__ beta,
        const int* __restrict__ oid, const uint* __restrict__ ktab,
        float* __restrict__ pairs_part, int n) {
  __shared__ __align__(16) uint skt[TK * KTW];   // 1 KiB
  const int tid = threadIdx.x;
  const int tile0 = blockIdx.y * TK;
  const int hbase = blockIdx.x * HCH;

  for (int t = tid; t < TK * KTW; t += 256)
    skt[t] = ktab[(size_t)tile0 * KTW + t];
  __syncthreads();

  // load HB hits into registers
  uint yh[HB][4];
  float thr[HB], bh[HB], qi[HB];
  int own[HB];
  const float4* xp = (const float4*)x;
  #pragma unroll
  for (int h = 0; h < HB; h++) {
    int i = hbase + h * 256 + tid;
    if (i < n) {
      float4 xa = xp[2 * (size_t)i];
      float4 xb = xp[2 * (size_t)i + 1];
      float xi[8] = {xa.x, xa.y, xa.z, xa.w, xb.x, xb.y, xb.z, xb.w};
      float s = 0.f;
      #pragma unroll
      for (int c = 0; c < 8; c++) s = fmaf(xi[c], xi[c], s);
      bh[h] = s;
      thr[h] = 1.f - s;     // accept iff d2' < thr  (d2 = d2' + |xi|^2 < 1)
      #pragma unroll
      for (int c = 0; c < 4; c++) {
        half2_t hy = { (_Float16)(-2.f * xi[2*c]), (_Float16)(-2.f * xi[2*c+1]) };
        yh[h][c] = __builtin_bit_cast(uint, hy);
      }
      qi[h] = q_of_beta(beta[i]);
      own[h] = oid[i] - 1 - tile0;   // own object within tile (or out of range)
    } else {
      #pragma unroll
      for (int c = 0; c < 4; c++) yh[h][c] = 0u;
      bh[h] = 0.f;
      thr[h] = -1e30f;               // never accept
      qi[h] = 0.f;
      own[h] = -1;
    }
  }

  float att = 0.f, rep = 0.f, nrep = 0.f;
  #pragma unroll 2
  for (int k = 0; k < TK; k++) {
    const uint* kr = &skt[k * KTW];
    uint4 kx = *(const uint4*)kr;            // ds_read_b128, wave-uniform
    float s2 = __uint_as_float(kr[4]);
    float wr = __uint_as_float(kr[5]);
    #pragma unroll
    for (int h = 0; h < HB; h++) {
      float dp = dot8h(kx, yh[h], s2);       // s2 - 2*xi.xk (fp16 in, fp32 acc)
      if (dp < thr[h]) {                     // d2 < 1
        float d2 = dp + bh[h];
        float dist = sqrtf(fmaxf(d2, 1e-12f));
        rep = fmaf(qi[h] * (1.f - dist), wr, rep);
        nrep += 1.f;
      }
    }
  }

  // own-object: attractive term + bit-exact undo of in-loop repulsive term
  #pragma unroll
  for (int h = 0; h < HB; h++) {
    int ko = own[h];
    if (ko >= 0 && ko < TK) {
      const uint* kr = &skt[ko * KTW];
      uint4 kx = *(const uint4*)kr;
      float s2 = __uint_as_float(kr[4]);
      float wr = __uint_as_float(kr[5]);
      float wa = __uint_as_float(kr[6]);
      float dp = dot8h(kx, yh[h], s2);       // identical op order -> same bits
      float d2 = dp + bh[h];
      att = fmaf(qi[h] * fmaxf(d2, 0.f), wa, att);
      if (dp < thr[h]) {
        float dist = sqrtf(fmaxf(d2, 1e-12f));
        rep = fmaf(-qi[h] * (1.f - dist), wr, rep);
        nrep -= 1.f;
      }
    }
  }

  att = wave_red_f(att);
  rep = wave_red_f(rep);
  nrep = wave_red_f(nrep);
  __shared__ float sred[4][3];
  int w = tid >> 6, l = tid & 63;
  if (l == 0) { sred[w][0] = att; sred[w][1] = rep; sred[w][2] = nrep; }
  __syncthreads();
  if (tid == 0) {
    int bid = blockIdx.y * gridDim.x + blockIdx.x;
    pairs_part[bid * 4 + 0] = sred[0][0]+sred[1][0]+sred[2][0]+sred[3][0];
    pairs_part[bid * 4 + 1] = sred[0][1]+sred[1][1]+sred[2][1]+sred[3][1];
    pairs_part[bid * 4 + 2] = sred[0][2]+sred[1][2]+sred[2][2]+sred[3][2];
  }
}

// ---------------------------------------------------------------------------
// Pass 4: combine everything.
// ---------------------------------------------------------------------------
__global__ __launch_bounds__(256) void
k_finalize(const float* __restrict__ pairs_part, int nblk_tot,
           const float* __restrict__ scal_part,
           const float* __restrict__ cow_part, float* __restrict__ out) {
  float v[9] = {0,0,0,0,0,0,0,0,0};  // att, rep, nrep, e, p, pid, noise, ncnt, mcnt
  for (int b = threadIdx.x; b < nblk_tot; b += 256) {
    v[0] += pairs_part[b * 4 + 0];
    v[1] += pairs_part[b * 4 + 1];
    v[2] += pairs_part[b * 4 + 2];
  }
  for (int m = threadIdx.x; m < MPREP; m += 256) {
    #pragma unroll
    for (int j = 0; j < 6; j++) v[3 + j] += scal_part[m * 8 + j];
  }
  #pragma unroll
  for (int j = 0; j < 9; j++) v[j] = wave_red_f(v[j]);
  __shared__ float sred[4][9];
  int w = threadIdx.x >> 6, l = threadIdx.x & 63;
  if (l == 0) {
    #pragma unroll
    for (int j = 0; j < 9; j++) sred[w][j] = v[j];
  }
  __syncthreads();
  if (threadIdx.x == 0) {
    float t[9];
    #pragma unroll
    for (int j = 0; j < 9; j++) t[j] = sred[0][j]+sred[1][j]+sred[2][j]+sred[3][j];
    float cow = 0.f;
    #pragma unroll
    for (int g = 0; g < GGATH; g++) cow += cow_part[g];
    float v_att  = t[0] / (float)KOBJ;
    float v_rep  = t[1] / (float)KOBJ;
    float n_rep  = t[2];
    float l_cow  = cow / (float)KOBJ;
    float l_noise = t[6] / t[7];
    float oc = v_att + v_rep + l_cow + l_noise;
    float nm = t[8];
    float e_loss  = t[3] / nm;
    float p_loss  = t[4] / (nm * 3.f);
    float pid_loss = t[5] / nm;
    out[0] = v_att;
    out[1] = v_rep;
    out[2] = l_cow;
    out[3] = l_noise;
    out[4] = n_rep;
    out[5] = oc;
    out[6] = e_loss;
    out[7] = p_loss;
    out[8] = pid_loss;
    out[9] = oc + e_loss + p_loss + pid_loss;
  }
}

extern "C" void kernel_launch(void* const* d_in, const int* in_sizes, int n_in,
                              void* d_out, int out_size, void* d_ws, size_t ws_size,
                              hipStream_t stream) {
  const float* beta   = (const float*)d_in[0];
  const float* x      = (const float*)d_in[1];
  const int*   oid    = (const int*)d_in[2];
  const float* energy = (const float*)d_in[3];
  const float* eph    = (const float*)d_in[4];
  const float* mom    = (const float*)d_in[5];
  const float* mph    = (const float*)d_in[6];
  const float* logits = (const float*)d_in[7];
  const int*   pid    = (const int*)d_in[8];
  float* out = (float*)d_out;
  const int n = in_sizes[0];
  const int nhb = (n + HCH - 1) / HCH;      // hit-chunks (59)
  const int nblk_tot = nhb * NTILE;         // 944

  char* base = (char*)d_ws;
  size_t off = 0;
  uint*  ktab       = (uint*)(base + off);  off += (size_t)KOBJ * KTW * 4;
  float* cow_part   = (float*)(base + off); off += GGATH * 4;
  float* pairs_part = (float*)(base + off); off += (size_t)nblk_tot * 4 * 4;
  off = (off + 255) & ~(size_t)255;
  unsigned long long* amax_part = (unsigned long long*)(base + off); off += (size_t)MPREP * KOBJ * 8;
  unsigned* cnt_part = (unsigned*)(base + off);                      off += (size_t)MPREP * KOBJ * 4;
  float* scal_part   = (float*)(base + off);                         off += (size_t)MPREP * 8 * 4;

  k_prep<<<MPREP, 256, 0, stream>>>(beta, oid, energy, eph, mom, mph, logits, pid,
                                    amax_part, cnt_part, scal_part, n);
  k_gather<<<GGATH, 256, 0, stream>>>(x, beta, amax_part, cnt_part, ktab, cow_part, n);
  k_pairs<<<dim3(nhb, NTILE), 256, 0, stream>>>(x, beta, oid, ktab, pairs_part, n);
  k_finalize<<<1, 256, 0, stream>>>(pairs_part, nblk_tot, scal_part, cow_part, out);
}